// Round 3
// baseline (3493.607 us; speedup 1.0000x reference)
//
#include <hip/hip_runtime.h>

// ---------------------------------------------------------------------------
// Seq2seq LSTM (B=256, S=336, F=8, H=512, P=96) on MI355X.
// Persistent cooperative kernel: 256 blocks = 16 batch-groups x 16 unit-groups.
// Weights in VGPRs (MFMA-fragment-packed f16). h exchanged via Infinity Cache
// with RELAXED agent atomics. Per-producer-WAVE monotonic flags (no RMW, no
// broadcast barrier); ONE __syncthreads per step; decoder y-feedback folded
// into the recurrent weights (rank-1 update) so y is off the critical path.
// ---------------------------------------------------------------------------

typedef _Float16 half8 __attribute__((ext_vector_type(8)));
typedef float f32x4 __attribute__((ext_vector_type(4)));
typedef unsigned long long ull;

#define B_SZ 256
#define S_LEN 336
#define P_LEN 96
#define H_SZ 512
#define T_TOT (S_LEN + P_LEN)   // 432

// workspace layout (bytes)
#define SZ_PACK (16*8*17*64*8*2)          // 2,228,224 per weight set
#define OFF_PACK 0                        // 3 sets: enc, dec_plain, dec_folded
#define OFF_HBUF (3*SZ_PACK)
#define SZ_HBUF (2*B_SZ*H_SZ*2)           // double-buffered h, f16
#define OFF_YBUF (OFF_HBUF + SZ_HBUF)
#define SZ_YBUF (P_LEN*B_SZ*4)            // y partial sums, fp32
#define OFF_FLG (OFF_YBUF + SZ_YBUF)
#define SZ_FLG (16*128*4)                 // per-(bg, producer-wave) flags

__device__ __forceinline__ float sigf(float x){
  return __builtin_amdgcn_rcpf(1.f + __expf(-x));
}
__device__ __forceinline__ float tanh_fast(float x){
  return 2.f*__builtin_amdgcn_rcpf(1.f + __expf(-2.f*x)) - 1.f;
}

// Pack weights into MFMA B-fragment order, f16.
// mode 0: enc_Whh, tail k=512..519 = enc_Wih columns
// mode 1: dec_Whh, tail k=512 = dec_Wih            (used only at t==S_LEN)
// mode 2: dec_Whh + dec_Wih*lin_W^T (rank-1 fold), tail zero (t>S_LEN)
__global__ void pack_weights(const float* __restrict__ Whh,
                             const float* __restrict__ Wih,
                             const float* __restrict__ linW,
                             _Float16* __restrict__ dst, int mode){
  int lane = threadIdx.x;
  int s = blockIdx.x, w = blockIdx.y, og = blockIdx.z;
  int col16 = lane & 15, hi = lane >> 4;
  int gatei = col16 >> 2, uloc = col16 & 3;
  int grow = gatei*H_SZ + og*32 + w*4 + uloc;   // row of the (2048 x 512) weight
  half8 v;
  #pragma unroll
  for (int j = 0; j < 8; j++){
    int k = s*32 + hi*8 + j;
    float x = 0.f;
    if (k < H_SZ){
      x = Whh[(size_t)grow*H_SZ + k];
      if (mode == 2) x += Wih[grow]*linW[k];
    } else if (mode == 0 && k < H_SZ + 8){
      x = Wih[(size_t)grow*8 + (k - H_SZ)];
    } else if (mode == 1 && k == H_SZ){
      x = Wih[grow];
    }
    v[j] = (_Float16)x;
  }
  *(half8*)(dst + ((size_t)(((og*8 + w)*17 + s)*64 + lane))*8) = v;
}

__global__ void finalize_out(const float* __restrict__ y_buf,
                             const float* __restrict__ lin_b,
                             float* __restrict__ out){
  int i = blockIdx.x*256 + threadIdx.x;        // i = b*96 + td
  int b = i / P_LEN, td = i % P_LEN;
  out[i] = y_buf[td*B_SZ + b] + lin_b[0];
}

__global__ __launch_bounds__(512) void lstm_main(
    const float* __restrict__ x_enc, const float* __restrict__ enc_b,
    const float* __restrict__ dec_b, const float* __restrict__ dec_Wih,
    const float* __restrict__ lin_W, const float* __restrict__ lin_b,
    const _Float16* __restrict__ pack,      // 3 packed weight sets
    ull* __restrict__ h_buf,                // [2][256 rows][128 ull]
    float* __restrict__ y_buf,
    unsigned int* __restrict__ flags)       // [16 bg][128 producer waves]
{
  const int bx = blockIdx.x;
  const int og = bx >> 4, bg = bx & 15;
  const int tid = threadIdx.x;
  const int w = tid >> 6, lane = tid & 63;
  const int col16 = lane & 15, hi = lane >> 4;
  const int gatei = col16 >> 2;             // 0:i 1:f 2:g 3:o
  const int q4 = col16 & 3;
  const int unit = og*32 + w*4 + q4;
  const int grow = gatei*H_SZ + unit;
  const int r0 = bg*16;                     // base batch row

  // A-tile, parity double-buffered: 16 rows x 1152B, XOR-swizzled
  __shared__ __align__(16) unsigned char Abuf[2][16*1152];

  const _Float16* packBase = pack + ((size_t)((og*8 + w)*17)*64 + lane)*8;
  const size_t setStride = (size_t)SZ_PACK/2;       // elements (f16)

  half8 Breg[17];
  #pragma unroll
  for (int s = 0; s < 17; s++)
    Breg[s] = *(const half8*)(packBase + (size_t)s*64*8);

  const float encb = enc_b[grow];
  const float decb = dec_b[grow];
  const float wihg = dec_Wih[grow];
  const float linw = lin_W[unit];
  const float lbv  = lin_b[0];
  float bias = encb;
  float c4[4] = {0.f, 0.f, 0.f, 0.f};      // cell state, resident all 432 steps

  const int srow = tid >> 5, sseg = tid & 31;    // staging: 16 rows x 32 segs
  const int ssw  = (srow & 7) << 4;
  const int abase = col16*1152;
  const int asw   = (col16 & 7) << 4;
  unsigned int* myflags = flags + bg*128;

  for (int t = 0; t < T_TOT; t++){
    unsigned char* Ab = Abuf[t & 1];

    if (t == S_LEN){                        // dec-plain (x_dec0 step)
      #pragma unroll
      for (int s = 0; s < 17; s++)
        Breg[s] = *(const half8*)(packBase + setStride + (size_t)s*64*8);
      bias = decb;
    } else if (t == S_LEN + 1){             // dec-folded (y feedback in Whh)
      #pragma unroll
      for (int s = 0; s < 17; s++)
        Breg[s] = *(const half8*)(packBase + 2*setStride + (size_t)s*64*8);
      bias = decb + wihg*lbv;
    }

    // early x load (independent of flags -> hides HBM/LLC latency)
    float xv = 0.f;
    if (t < S_LEN){
      if (tid < 128)
        xv = x_enc[(size_t)(r0 + (tid >> 3))*(S_LEN*8) + t*8 + (tid & 7)];
    } else if (t == S_LEN){
      if (tid < 16)
        xv = x_enc[(size_t)(r0 + tid)*(S_LEN*8) + 335*8 + 3];
    }

    if (t > 0){
      // per-lane poll: the 4 producer waves covering this lane's 32B segment
      const ull* fl = (const ull*)myflags + sseg*2;
      const unsigned tgt = (unsigned)t;
      for(;;){
        ull f0 = __hip_atomic_load(fl+0, __ATOMIC_RELAXED, __HIP_MEMORY_SCOPE_AGENT);
        ull f1 = __hip_atomic_load(fl+1, __ATOMIC_RELAXED, __HIP_MEMORY_SCOPE_AGENT);
        if ((unsigned)f0 >= tgt && (unsigned)(f0 >> 32) >= tgt &&
            (unsigned)f1 >= tgt && (unsigned)(f1 >> 32) >= tgt) break;
      }
      const ull* hs = h_buf + ((size_t)(((t-1)&1)*B_SZ + r0 + srow))*128 + sseg*4;
      ull d0 = __hip_atomic_load(hs+0, __ATOMIC_RELAXED, __HIP_MEMORY_SCOPE_AGENT);
      ull d1 = __hip_atomic_load(hs+1, __ATOMIC_RELAXED, __HIP_MEMORY_SCOPE_AGENT);
      ull d2 = __hip_atomic_load(hs+2, __ATOMIC_RELAXED, __HIP_MEMORY_SCOPE_AGENT);
      ull d3 = __hip_atomic_load(hs+3, __ATOMIC_RELAXED, __HIP_MEMORY_SCOPE_AGENT);
      uint4 A;  A.x = (unsigned)d0; A.y = (unsigned)(d0>>32);
                A.z = (unsigned)d1; A.w = (unsigned)(d1>>32);
      uint4 Bv; Bv.x = (unsigned)d2; Bv.y = (unsigned)(d2>>32);
                Bv.z = (unsigned)d3; Bv.w = (unsigned)(d3>>32);
      *(uint4*)&Ab[srow*1152 + ((sseg*32     ) ^ ssw)] = A;
      *(uint4*)&Ab[srow*1152 + ((sseg*32 + 16) ^ ssw)] = Bv;
    }

    // stage x tail
    if (t < S_LEN){
      if (tid < 128){
        int r = tid >> 3, f = tid & 7;
        *(_Float16*)&Ab[r*1152 + (1024 ^ ((r & 7) << 4)) + f*2] = (_Float16)xv;
      }
      if (t == 0 && tid >= 256 && tid < 352){
        int idx = tid - 256;                 // zero k=520..543 of BOTH buffers once
        int bsel = idx / 48, rem = idx % 48;
        int r = rem & 15, u = 1 + (rem >> 4);
        uint4 z = {0, 0, 0, 0};
        *(uint4*)&Abuf[bsel][r*1152 + ((1024 + u*16) ^ ((r & 7) << 4))] = z;
      }
    } else if (t == S_LEN){
      if (tid < 16){
        half8 va;
        #pragma unroll
        for (int q = 0; q < 8; q++) va[q] = (_Float16)0.f;
        va[0] = (_Float16)xv;
        *(half8*)&Ab[tid*1152 + (1024 ^ ((tid & 7) << 4))] = va;
      }
    }
    __syncthreads();   // the ONLY barrier per step

    // gates = bias + [h | x] @ W^T
    f32x4 acc = {bias, bias, bias, bias};
    if (t == 0){       // h0 = 0: only the x K-tile contributes
      half8 a = *(const half8*)&Ab[abase + ((1024 + hi*16) ^ asw)];
      acc = __builtin_amdgcn_mfma_f32_16x16x32_f16(a, Breg[16], acc, 0, 0, 0);
    } else {
      f32x4 acc1 = {0.f, 0.f, 0.f, 0.f};
      #pragma unroll
      for (int s = 0; s < 16; s += 2){
        half8 a0 = *(const half8*)&Ab[abase + (((s  )*64 + hi*16) ^ asw)];
        half8 a1 = *(const half8*)&Ab[abase + (((s+1)*64 + hi*16) ^ asw)];
        acc  = __builtin_amdgcn_mfma_f32_16x16x32_f16(a0, Breg[s],   acc,  0, 0, 0);
        acc1 = __builtin_amdgcn_mfma_f32_16x16x32_f16(a1, Breg[s+1], acc1, 0, 0, 0);
      }
      if (t <= S_LEN){   // x/x_dec0 tail frag; folded decoder steps skip it
        half8 a16 = *(const half8*)&Ab[abase + ((16*64 + hi*16) ^ asw)];
        acc = __builtin_amdgcn_mfma_f32_16x16x32_f16(a16, Breg[16], acc, 0, 0, 0);
      }
      acc = acc + acc1;
    }

    // LSTM pointwise: gather i,f,g,o across lanes c, c^4, c^8, c^12
    float hold[4];
    #pragma unroll
    for (int j = 0; j < 4; j++){
      float a   = acc[j];
      float x4  = __shfl_xor(a, 4);
      float x8  = __shfl_xor(a, 8);
      float x12 = __shfl_xor(x4, 8);
      float gi, gf, gg, go;
      if      (gatei == 0){ gi = a;   gf = x4;  gg = x8;  go = x12; }
      else if (gatei == 1){ gi = x4;  gf = a;   gg = x12; go = x8;  }
      else if (gatei == 2){ gi = x8;  gf = x12; gg = a;   go = x4;  }
      else                { gi = x12; gf = x8;  gg = x4;  go = a;   }
      float cn = sigf(gf)*c4[j] + sigf(gi)*tanh_fast(gg);
      c4[j] = cn;
      hold[j] = sigf(go)*tanh_fast(cn);
    }

    // 4x4 lane transpose within each col16-quad -> one 8B LLC store per lane
    unsigned short s16[4];
    #pragma unroll
    for (int j = 0; j < 4; j++)
      s16[j] = __builtin_bit_cast(unsigned short, (_Float16)hold[j]);
    unsigned lo01 = (unsigned)s16[0] | ((unsigned)s16[1] << 16);
    unsigned hi23 = (unsigned)s16[2] | ((unsigned)s16[3] << 16);
    const bool qlow = (q4 < 2), up = (q4 & 1);
    unsigned sendA = qlow ? hi23 : lo01;
    unsigned rA    = (unsigned)__shfl_xor((int)sendA, 2);
    unsigned keepA = qlow ? lo01 : hi23;
    unsigned vq_p  = up ? (keepA & 0xffffu) : (keepA >> 16);
    unsigned vqx_p = up ? (rA    & 0xffffu) : (rA    >> 16);
    unsigned sendB = qlow ? (vq_p | (vqx_p << 16)) : (vqx_p | (vq_p << 16));
    unsigned rB    = (unsigned)__shfl_xor((int)sendB, 1);
    unsigned vq_m  = up ? (keepA >> 16) : (keepA & 0xffffu);
    unsigned vqx_m = up ? (rA    >> 16) : (rA    & 0xffffu);
    unsigned ownB  = qlow ? (vq_m | (vqx_m << 16)) : (vqx_m | (vq_m << 16));
    unsigned w0 = up ? ((rB & 0xffffu) | (ownB << 16)) : ((ownB & 0xffffu) | (rB << 16));
    unsigned w1 = up ? ((rB >> 16) | (ownB & 0xffff0000u))
                     : ((ownB >> 16) | (rB & 0xffff0000u));
    if (gatei == 0){
      ull hv = (ull)w0 | ((ull)w1 << 32);
      int row = hi*4 + q4;
      __hip_atomic_store(h_buf + ((size_t)((t&1)*B_SZ + r0 + row))*128 + og*8 + w,
                         hv, __ATOMIC_RELAXED, __HIP_MEMORY_SCOPE_AGENT);
    }

    // publish: own wave's h stores drained -> monotonic per-wave flag
    asm volatile("s_waitcnt vmcnt(0)" ::: "memory");
    if (lane == 0)
      __hip_atomic_store(&myflags[og*8 + w], (unsigned)(t + 1),
                         __ATOMIC_RELAXED, __HIP_MEMORY_SCOPE_AGENT);

    // decoder outputs: y partials AFTER the flag (off the critical path)
    if (t >= S_LEN){
      #pragma unroll
      for (int j = 0; j < 4; j++){
        float pv = (gatei == 0) ? hold[j]*linw : 0.f;
        pv += __shfl_xor(pv, 1);
        pv += __shfl_xor(pv, 2);
        if (col16 == 0)
          __hip_atomic_fetch_add(&y_buf[(t - S_LEN)*B_SZ + r0 + hi*4 + j], pv,
                                 __ATOMIC_RELAXED, __HIP_MEMORY_SCOPE_AGENT);
      }
    }
  }
}

extern "C" void kernel_launch(void* const* d_in, const int* in_sizes, int n_in,
                              void* d_out, int out_size, void* d_ws, size_t ws_size,
                              hipStream_t stream) {
  const float* x_enc   = (const float*)d_in[0];
  const float* enc_Wih = (const float*)d_in[1];
  const float* enc_Whh = (const float*)d_in[2];
  const float* enc_b   = (const float*)d_in[3];
  const float* dec_Wih = (const float*)d_in[4];
  const float* dec_Whh = (const float*)d_in[5];
  const float* dec_b   = (const float*)d_in[6];
  const float* lin_W   = (const float*)d_in[7];
  const float* lin_b   = (const float*)d_in[8];

  char* ws = (char*)d_ws;
  _Float16* pack  = (_Float16*)(ws + OFF_PACK);
  ull*      h_buf = (ull*)(ws + OFF_HBUF);
  float*    y_buf = (float*)(ws + OFF_YBUF);
  unsigned int* flags = (unsigned int*)(ws + OFF_FLG);

  // zero y partials + flags (deterministic across graph replays)
  hipMemsetAsync(ws + OFF_YBUF, 0, SZ_YBUF + SZ_FLG, stream);

  pack_weights<<<dim3(17, 8, 16), 64, 0, stream>>>(enc_Whh, enc_Wih, lin_W,
                                                   pack, 0);
  pack_weights<<<dim3(17, 8, 16), 64, 0, stream>>>(dec_Whh, dec_Wih, lin_W,
                                                   pack + SZ_PACK/2, 1);
  pack_weights<<<dim3(17, 8, 16), 64, 0, stream>>>(dec_Whh, dec_Wih, lin_W,
                                                   pack + SZ_PACK, 2);

  void* args[] = { (void*)&x_enc, (void*)&enc_b, (void*)&dec_b, (void*)&dec_Wih,
                   (void*)&lin_W, (void*)&lin_b, (void*)&pack,
                   (void*)&h_buf, (void*)&y_buf, (void*)&flags };
  hipLaunchCooperativeKernel((void*)lstm_main, dim3(256), dim3(512),
                             args, 0, stream);

  finalize_out<<<dim3((B_SZ*P_LEN)/256), 256, 0, stream>>>(y_buf, lin_b, (float*)d_out);
}

// Round 6
// 2510.875 us; speedup vs baseline: 1.3914x; 1.3914x over previous
//
#include <hip/hip_runtime.h>

// ---------------------------------------------------------------------------
// Seq2seq LSTM (B=256, S=336, F=8, H=512, P=96) on MI355X.
// Persistent cooperative kernel: 256 blocks = 16 batch-groups x 16 unit-groups.
// Weights in VGPRs (MFMA-fragment-packed f16). h exchanged via LLC with
// per-producer-wave monotonic flags (plain relaxed stores, no RMW).
// ONE wave per block polls (64 lanes x one 8B word = 128 flags), then
// __syncthreads broadcasts. Decoder y-feedback folded into Whh (rank-1);
// y partials in conflict-free per-(og,wave) slots summed by finalize_out.
// All cross-block ops: __hip_atomic_* RELAXED/AGENT (proven R2/R3) only.
// ---------------------------------------------------------------------------

typedef _Float16 half8 __attribute__((ext_vector_type(8)));
typedef float f32x4 __attribute__((ext_vector_type(4)));
typedef unsigned long long ull;

#define B_SZ 256
#define S_LEN 336
#define P_LEN 96
#define H_SZ 512
#define T_TOT (S_LEN + P_LEN)   // 432

// workspace layout (bytes)
#define SZ_PACK (16*8*17*64*8*2)          // 2,228,224 per weight set
#define OFF_PACK 0                        // 3 sets: enc, dec_plain, dec_folded
#define OFF_HBUF (3*SZ_PACK)
#define SZ_HBUF (2*B_SZ*H_SZ*2)           // double-buffered h, f16
#define OFF_YBUF (OFF_HBUF + SZ_HBUF)
#define SZ_YBUF (P_LEN*B_SZ*128*4)        // y partials, [td][b][og*8+w] fp32
#define OFF_FLG (OFF_YBUF + SZ_YBUF)
#define SZ_FLG (16*128*4)                 // per-(bg, producer-wave) flags

__device__ __forceinline__ float sigf(float x){
  return __builtin_amdgcn_rcpf(1.f + __expf(-x));
}
__device__ __forceinline__ float tanh_fast(float x){
  return 2.f*__builtin_amdgcn_rcpf(1.f + __expf(-2.f*x)) - 1.f;
}

// Pack weights into MFMA B-fragment order, f16.
// mode 0: enc_Whh, tail k=512..519 = enc_Wih columns
// mode 1: dec_Whh, tail k=512 = dec_Wih            (used only at t==S_LEN)
// mode 2: dec_Whh + dec_Wih*lin_W^T (rank-1 fold), tail zero (t>S_LEN)
__global__ void pack_weights(const float* __restrict__ Whh,
                             const float* __restrict__ Wih,
                             const float* __restrict__ linW,
                             _Float16* __restrict__ dst, int mode){
  int lane = threadIdx.x;
  int s = blockIdx.x, w = blockIdx.y, og = blockIdx.z;
  int col16 = lane & 15, hi = lane >> 4;
  int gatei = col16 >> 2, uloc = col16 & 3;
  int grow = gatei*H_SZ + og*32 + w*4 + uloc;   // row of the (2048 x 512) weight
  half8 v;
  #pragma unroll
  for (int j = 0; j < 8; j++){
    int k = s*32 + hi*8 + j;
    float x = 0.f;
    if (k < H_SZ){
      x = Whh[(size_t)grow*H_SZ + k];
      if (mode == 2) x += Wih[grow]*linW[k];
    } else if (mode == 0 && k < H_SZ + 8){
      x = Wih[(size_t)grow*8 + (k - H_SZ)];
    } else if (mode == 1 && k == H_SZ){
      x = Wih[grow];
    }
    v[j] = (_Float16)x;
  }
  *(half8*)(dst + ((size_t)(((og*8 + w)*17 + s)*64 + lane))*8) = v;
}

__global__ void finalize_out(const float* __restrict__ y_buf,
                             const float* __restrict__ lin_b,
                             float* __restrict__ out){
  int i = blockIdx.x*256 + threadIdx.x;        // i = b*96 + td
  int b = i / P_LEN, td = i % P_LEN;
  const float* p = y_buf + ((size_t)td*B_SZ + b)*128;
  float s = lin_b[0];
  #pragma unroll
  for (int q = 0; q < 128; q++) s += p[q];
  out[i] = s;
}

__global__ __launch_bounds__(512) void lstm_main(
    const float* __restrict__ x_enc, const float* __restrict__ enc_b,
    const float* __restrict__ dec_b, const float* __restrict__ dec_Wih,
    const float* __restrict__ lin_W, const float* __restrict__ lin_b,
    const _Float16* __restrict__ pack,      // 3 packed weight sets
    ull* __restrict__ h_buf,                // [2][256 rows][128 ull]
    float* __restrict__ y_buf,              // [96][256][128]
    unsigned int* __restrict__ flags)       // [16 bg][128 producer waves]
{
  const int bx = blockIdx.x;
  const int og = bx >> 4, bg = bx & 15;
  const int tid = threadIdx.x;
  const int w = tid >> 6, lane = tid & 63;
  const int col16 = lane & 15, hi = lane >> 4;
  const int gatei = col16 >> 2;             // 0:i 1:f 2:g 3:o
  const int q4 = col16 & 3;
  const int unit = og*32 + w*4 + q4;
  const int grow = gatei*H_SZ + unit;
  const int r0 = bg*16;                     // base batch row

  // A-tile: 16 rows x 1152B (512 h-f16 + x/y tail), XOR-swizzled
  __shared__ __align__(16) unsigned char Abuf[16*1152];

  const _Float16* packBase = pack + ((size_t)((og*8 + w)*17)*64 + lane)*8;
  const size_t setStride = (size_t)SZ_PACK/2;       // elements (f16)

  half8 Breg[17];
  #pragma unroll
  for (int s = 0; s < 17; s++)
    Breg[s] = *(const half8*)(packBase + (size_t)s*64*8);

  const float encb = enc_b[grow];
  const float decb = dec_b[grow];
  const float wihg = dec_Wih[grow];
  const float linw = lin_W[unit];
  const float lbv  = lin_b[0];
  float bias = encb;
  float c4[4] = {0.f, 0.f, 0.f, 0.f};      // cell state, resident all 432 steps

  const int srow = tid >> 5, sseg = tid & 31;    // staging: 16 rows x 32 segs
  const int ssw  = (srow & 7) << 4;
  const int abase = col16*1152;
  const int asw   = (col16 & 7) << 4;
  unsigned int* myflags = flags + bg*128;

  for (int t = 0; t < T_TOT; t++){
    if (t == S_LEN){                        // dec-plain (x_dec0 step)
      #pragma unroll
      for (int s = 0; s < 17; s++)
        Breg[s] = *(const half8*)(packBase + setStride + (size_t)s*64*8);
      bias = decb;
    } else if (t == S_LEN + 1){             // dec-folded (y feedback in Whh)
      #pragma unroll
      for (int s = 0; s < 17; s++)
        Breg[s] = *(const half8*)(packBase + 2*setStride + (size_t)s*64*8);
      bias = decb + wihg*lbv;
    }

    // early x load (read-only, plain cached -> hides latency under poll)
    float xv = 0.f;
    if (t < S_LEN){
      if (tid < 128)
        xv = x_enc[(size_t)(r0 + (tid >> 3))*(S_LEN*8) + t*8 + (tid & 7)];
    } else if (t == S_LEN){
      if (tid < 16)
        xv = x_enc[(size_t)(r0 + tid)*(S_LEN*8) + 335*8 + 3];
    }

    // ---- wait for producers: ONE wave polls (lane l -> flags[2l..2l+1])
    if (t > 0 && w == 0){
      const ull* fp = (const ull*)myflags + lane;
      const unsigned tgt = (unsigned)t;
      for(;;){
        ull f = __hip_atomic_load(fp, __ATOMIC_RELAXED, __HIP_MEMORY_SCOPE_AGENT);
        bool ok = ((unsigned)f >= tgt) && ((unsigned)(f >> 32) >= tgt);
        if (__all(ok)) break;
      }
    }
    __syncthreads();   // B1: h ready; prev step's MFMA reads of Abuf done

    // ---- stage h_{t-1} (coalesced 32B/thread -> swizzled LDS)
    if (t > 0){
      const ull* hs = h_buf + ((size_t)(((t-1)&1)*B_SZ + r0 + srow))*128 + sseg*4;
      ull d0 = __hip_atomic_load(hs+0, __ATOMIC_RELAXED, __HIP_MEMORY_SCOPE_AGENT);
      ull d1 = __hip_atomic_load(hs+1, __ATOMIC_RELAXED, __HIP_MEMORY_SCOPE_AGENT);
      ull d2 = __hip_atomic_load(hs+2, __ATOMIC_RELAXED, __HIP_MEMORY_SCOPE_AGENT);
      ull d3 = __hip_atomic_load(hs+3, __ATOMIC_RELAXED, __HIP_MEMORY_SCOPE_AGENT);
      uint4 A;  A.x = (unsigned)d0; A.y = (unsigned)(d0>>32);
                A.z = (unsigned)d1; A.w = (unsigned)(d1>>32);
      uint4 Bv; Bv.x = (unsigned)d2; Bv.y = (unsigned)(d2>>32);
                Bv.z = (unsigned)d3; Bv.w = (unsigned)(d3>>32);
      *(uint4*)&Abuf[srow*1152 + ((sseg*32     ) ^ ssw)] = A;
      *(uint4*)&Abuf[srow*1152 + ((sseg*32 + 16) ^ ssw)] = Bv;
    }
    // ---- stage x tail
    if (t < S_LEN){
      if (tid < 128){
        int r = tid >> 3, f = tid & 7;
        *(_Float16*)&Abuf[r*1152 + (1024 ^ ((r & 7) << 4)) + f*2] = (_Float16)xv;
      }
      if (t == 0 && tid >= 256 && tid < 304){
        int idx = tid - 256;                 // zero k=520..543 once (persists)
        int r = idx & 15, u = 1 + (idx >> 4);
        uint4 z = {0, 0, 0, 0};
        *(uint4*)&Abuf[r*1152 + ((1024 + u*16) ^ ((r & 7) << 4))] = z;
      }
    } else if (t == S_LEN){
      if (tid < 16){
        half8 va;
        #pragma unroll
        for (int q = 0; q < 8; q++) va[q] = (_Float16)0.f;
        va[0] = (_Float16)xv;
        *(half8*)&Abuf[tid*1152 + (1024 ^ ((tid & 7) << 4))] = va;
      }
    }
    __syncthreads();   // B2: A-tile complete

    // ---- gates = bias + [h | x] @ W^T
    f32x4 acc = {bias, bias, bias, bias};
    if (t == 0){       // h0 = 0: only the x K-tile contributes
      half8 a = *(const half8*)&Abuf[abase + ((1024 + hi*16) ^ asw)];
      acc = __builtin_amdgcn_mfma_f32_16x16x32_f16(a, Breg[16], acc, 0, 0, 0);
    } else {
      f32x4 acc1 = {0.f, 0.f, 0.f, 0.f};
      #pragma unroll
      for (int s = 0; s < 16; s += 2){
        half8 a0 = *(const half8*)&Abuf[abase + (((s  )*64 + hi*16) ^ asw)];
        half8 a1 = *(const half8*)&Abuf[abase + (((s+1)*64 + hi*16) ^ asw)];
        acc  = __builtin_amdgcn_mfma_f32_16x16x32_f16(a0, Breg[s],   acc,  0, 0, 0);
        acc1 = __builtin_amdgcn_mfma_f32_16x16x32_f16(a1, Breg[s+1], acc1, 0, 0, 0);
      }
      if (t <= S_LEN){   // x/x_dec0 tail frag; folded decoder steps skip it
        half8 a16 = *(const half8*)&Abuf[abase + ((16*64 + hi*16) ^ asw)];
        acc = __builtin_amdgcn_mfma_f32_16x16x32_f16(a16, Breg[16], acc, 0, 0, 0);
      }
      acc = acc + acc1;
    }

    // ---- LSTM pointwise: gather i,f,g,o across lanes c, c^4, c^8, c^12
    float hold[4];
    #pragma unroll
    for (int j = 0; j < 4; j++){
      float a   = acc[j];
      float x4  = __shfl_xor(a, 4);
      float x8  = __shfl_xor(a, 8);
      float x12 = __shfl_xor(x4, 8);
      float gi, gf, gg, go;
      if      (gatei == 0){ gi = a;   gf = x4;  gg = x8;  go = x12; }
      else if (gatei == 1){ gi = x4;  gf = a;   gg = x12; go = x8;  }
      else if (gatei == 2){ gi = x8;  gf = x12; gg = a;   go = x4;  }
      else                { gi = x12; gf = x8;  gg = x4;  go = a;   }
      float cn = sigf(gf)*c4[j] + sigf(gi)*tanh_fast(gg);
      c4[j] = cn;
      hold[j] = sigf(go)*tanh_fast(cn);
    }

    // ---- 4x4 lane transpose within each col16-quad -> one 8B store per lane
    unsigned short s16[4];
    #pragma unroll
    for (int j = 0; j < 4; j++)
      s16[j] = __builtin_bit_cast(unsigned short, (_Float16)hold[j]);
    unsigned lo01 = (unsigned)s16[0] | ((unsigned)s16[1] << 16);
    unsigned hi23 = (unsigned)s16[2] | ((unsigned)s16[3] << 16);
    const bool qlow = (q4 < 2), up = (q4 & 1);
    unsigned sendA = qlow ? hi23 : lo01;
    unsigned rA    = (unsigned)__shfl_xor((int)sendA, 2);
    unsigned keepA = qlow ? lo01 : hi23;
    unsigned vq_p  = up ? (keepA & 0xffffu) : (keepA >> 16);
    unsigned vqx_p = up ? (rA    & 0xffffu) : (rA    >> 16);
    unsigned sendB = qlow ? (vq_p | (vqx_p << 16)) : (vqx_p | (vq_p << 16));
    unsigned rB    = (unsigned)__shfl_xor((int)sendB, 1);
    unsigned vq_m  = up ? (keepA >> 16) : (keepA & 0xffffu);
    unsigned vqx_m = up ? (rA    >> 16) : (rA    & 0xffffu);
    unsigned ownB  = qlow ? (vq_m | (vqx_m << 16)) : (vqx_m | (vq_m << 16));
    unsigned w0 = up ? ((rB & 0xffffu) | (ownB << 16)) : ((ownB & 0xffffu) | (rB << 16));
    unsigned w1 = up ? ((rB >> 16) | (ownB & 0xffff0000u))
                     : ((ownB >> 16) | (rB & 0xffff0000u));
    if (gatei == 0){
      ull hv = (ull)w0 | ((ull)w1 << 32);
      int row = hi*4 + q4;
      __hip_atomic_store(h_buf + ((size_t)((t&1)*B_SZ + r0 + row))*128 + og*8 + w,
                         hv, __ATOMIC_RELAXED, __HIP_MEMORY_SCOPE_AGENT);
    }

    // ---- publish: wave's h stores drained -> monotonic per-wave flag
    asm volatile("s_waitcnt vmcnt(0)" ::: "memory");
    if (lane == 0)
      __hip_atomic_store(&myflags[og*8 + w], (unsigned)(t + 1),
                         __ATOMIC_RELAXED, __HIP_MEMORY_SCOPE_AGENT);

    // ---- decoder outputs: conflict-free per-(og,wave) slot (off crit path)
    if (t >= S_LEN){
      #pragma unroll
      for (int j = 0; j < 4; j++){
        float pv = (gatei == 0) ? hold[j]*linw : 0.f;
        pv += __shfl_xor(pv, 1);
        pv += __shfl_xor(pv, 2);
        if (col16 == 0)
          __hip_atomic_store(
              &y_buf[((size_t)(t - S_LEN)*B_SZ + r0 + hi*4 + j)*128 + og*8 + w],
              pv, __ATOMIC_RELAXED, __HIP_MEMORY_SCOPE_AGENT);
      }
    }
  }
}

extern "C" void kernel_launch(void* const* d_in, const int* in_sizes, int n_in,
                              void* d_out, int out_size, void* d_ws, size_t ws_size,
                              hipStream_t stream) {
  const float* x_enc   = (const float*)d_in[0];
  const float* enc_Wih = (const float*)d_in[1];
  const float* enc_Whh = (const float*)d_in[2];
  const float* enc_b   = (const float*)d_in[3];
  const float* dec_Wih = (const float*)d_in[4];
  const float* dec_Whh = (const float*)d_in[5];
  const float* dec_b   = (const float*)d_in[6];
  const float* lin_W   = (const float*)d_in[7];
  const float* lin_b   = (const float*)d_in[8];

  char* ws = (char*)d_ws;
  _Float16* pack  = (_Float16*)(ws + OFF_PACK);
  ull*      h_buf = (ull*)(ws + OFF_HBUF);
  float*    y_buf = (float*)(ws + OFF_YBUF);
  unsigned int* flags = (unsigned int*)(ws + OFF_FLG);

  // zero flags (monotonic from 0 each launch; deterministic across replays)
  hipMemsetAsync(ws + OFF_FLG, 0, SZ_FLG, stream);

  pack_weights<<<dim3(17, 8, 16), 64, 0, stream>>>(enc_Whh, enc_Wih, lin_W,
                                                   pack, 0);
  pack_weights<<<dim3(17, 8, 16), 64, 0, stream>>>(dec_Whh, dec_Wih, lin_W,
                                                   pack + SZ_PACK/2, 1);
  pack_weights<<<dim3(17, 8, 16), 64, 0, stream>>>(dec_Whh, dec_Wih, lin_W,
                                                   pack + SZ_PACK, 2);

  void* args[] = { (void*)&x_enc, (void*)&enc_b, (void*)&dec_b, (void*)&dec_Wih,
                   (void*)&lin_W, (void*)&lin_b, (void*)&pack,
                   (void*)&h_buf, (void*)&y_buf, (void*)&flags };
  hipLaunchCooperativeKernel((void*)lstm_main, dim3(256), dim3(512),
                             args, 0, stream);

  finalize_out<<<dim3((B_SZ*P_LEN)/256), 256, 0, stream>>>(y_buf, lin_b, (float*)d_out);
}

// Round 7
// 2052.362 us; speedup vs baseline: 1.7022x; 1.2234x over previous
//
#include <hip/hip_runtime.h>

// ---------------------------------------------------------------------------
// Seq2seq LSTM (B=256, S=336, F=8, H=512, P=96) on MI355X.
// Persistent cooperative kernel: 256 blocks = 16 batch-groups x 16 unit-groups.
// Weights in VGPRs (MFMA-fragment-packed f16). h exchanged via LLC.
// Publish: per-wave vmcnt drain -> LDS arrival counter -> LAST wave stores ONE
// block flag (no RMW on globals). Consume: wave0 lanes 0-15 poll the bg's 16
// block flags (one 64B line), __all, __syncthreads. Decoder y-feedback folded
// into Whh (rank-1); y partials in per-(og,wave) slots summed by finalize_out.
// ---------------------------------------------------------------------------

typedef _Float16 half8 __attribute__((ext_vector_type(8)));
typedef float f32x4 __attribute__((ext_vector_type(4)));
typedef unsigned long long ull;

#define B_SZ 256
#define S_LEN 336
#define P_LEN 96
#define H_SZ 512
#define T_TOT (S_LEN + P_LEN)   // 432

// workspace layout (bytes)
#define SZ_PACK (16*8*17*64*8*2)          // 2,228,224 per weight set
#define OFF_PACK 0                        // 3 sets: enc, dec_plain, dec_folded
#define OFF_HBUF (3*SZ_PACK)
#define SZ_HBUF (2*B_SZ*H_SZ*2)           // double-buffered h, f16
#define OFF_YBUF (OFF_HBUF + SZ_HBUF)
#define SZ_YBUF (P_LEN*B_SZ*128*4)        // y partials, [td][b][og*8+w] fp32
#define OFF_FLG (OFF_YBUF + SZ_YBUF)
#define SZ_FLG (16*16*4)                  // [bg][og] block flags (64B per bg)

__device__ __forceinline__ float sigf(float x){
  return __builtin_amdgcn_rcpf(1.f + __expf(-x));
}
__device__ __forceinline__ float tanh_fast(float x){
  return 2.f*__builtin_amdgcn_rcpf(1.f + __expf(-2.f*x)) - 1.f;
}

// Pack weights into MFMA B-fragment order, f16.
// mode 0: enc_Whh, tail k=512..519 = enc_Wih columns
// mode 1: dec_Whh, tail k=512 = dec_Wih            (used only at t==S_LEN)
// mode 2: dec_Whh + dec_Wih*lin_W^T (rank-1 fold), tail zero (t>S_LEN)
__global__ void pack_weights(const float* __restrict__ Whh,
                             const float* __restrict__ Wih,
                             const float* __restrict__ linW,
                             _Float16* __restrict__ dst, int mode){
  int lane = threadIdx.x;
  int s = blockIdx.x, w = blockIdx.y, og = blockIdx.z;
  int col16 = lane & 15, hi = lane >> 4;
  int gatei = col16 >> 2, uloc = col16 & 3;
  int grow = gatei*H_SZ + og*32 + w*4 + uloc;   // row of the (2048 x 512) weight
  half8 v;
  #pragma unroll
  for (int j = 0; j < 8; j++){
    int k = s*32 + hi*8 + j;
    float x = 0.f;
    if (k < H_SZ){
      x = Whh[(size_t)grow*H_SZ + k];
      if (mode == 2) x += Wih[grow]*linW[k];
    } else if (mode == 0 && k < H_SZ + 8){
      x = Wih[(size_t)grow*8 + (k - H_SZ)];
    } else if (mode == 1 && k == H_SZ){
      x = Wih[grow];
    }
    v[j] = (_Float16)x;
  }
  *(half8*)(dst + ((size_t)(((og*8 + w)*17 + s)*64 + lane))*8) = v;
}

__global__ void finalize_out(const float* __restrict__ y_buf,
                             const float* __restrict__ lin_b,
                             float* __restrict__ out){
  int i = blockIdx.x*256 + threadIdx.x;        // i = b*96 + td
  int b = i / P_LEN, td = i % P_LEN;
  const float* p = y_buf + ((size_t)td*B_SZ + b)*128;
  float s = lin_b[0];
  #pragma unroll
  for (int q = 0; q < 128; q++) s += p[q];
  out[i] = s;
}

__global__ __launch_bounds__(512) void lstm_main(
    const float* __restrict__ x_enc, const float* __restrict__ enc_b,
    const float* __restrict__ dec_b, const float* __restrict__ dec_Wih,
    const float* __restrict__ lin_W, const float* __restrict__ lin_b,
    const _Float16* __restrict__ pack,      // 3 packed weight sets
    ull* __restrict__ h_buf,                // [2][256 rows][128 ull]
    float* __restrict__ y_buf,              // [96][256][128]
    unsigned int* __restrict__ blkflags)    // [16 bg][16 og]
{
  const int bx = blockIdx.x;
  const int og = bx >> 4, bg = bx & 15;
  const int tid = threadIdx.x;
  const int w = tid >> 6, lane = tid & 63;
  const int col16 = lane & 15, hi = lane >> 4;
  const int gatei = col16 >> 2;             // 0:i 1:f 2:g 3:o
  const int q4 = col16 & 3;
  const int unit = og*32 + w*4 + q4;
  const int grow = gatei*H_SZ + unit;
  const int r0 = bg*16;                     // base batch row

  // A-tile: 16 rows x 1152B (512 h-f16 + x/y tail), XOR-swizzled
  __shared__ __align__(16) unsigned char Abuf[16*1152];
  __shared__ unsigned lds_arrive;           // monotonic wave-arrival counter

  if (tid == 0) lds_arrive = 0;             // visible by first use (2 barriers)

  const _Float16* packBase = pack + ((size_t)((og*8 + w)*17)*64 + lane)*8;
  const size_t setStride = (size_t)SZ_PACK/2;       // elements (f16)

  half8 Breg[17];
  #pragma unroll
  for (int s = 0; s < 17; s++)
    Breg[s] = *(const half8*)(packBase + (size_t)s*64*8);

  const float encb = enc_b[grow];
  const float decb = dec_b[grow];
  const float wihg = dec_Wih[grow];
  const float linw = lin_W[unit];
  const float lbv  = lin_b[0];
  float bias = encb;
  float c4[4] = {0.f, 0.f, 0.f, 0.f};      // cell state, resident all 432 steps

  const int srow = tid >> 5, sseg = tid & 31;    // staging: 16 rows x 32 segs
  const int ssw  = (srow & 7) << 4;
  const int abase = col16*1152;
  const int asw   = (col16 & 7) << 4;

  for (int t = 0; t < T_TOT; t++){
    if (t == S_LEN){                        // dec-plain (x_dec0 step)
      #pragma unroll
      for (int s = 0; s < 17; s++)
        Breg[s] = *(const half8*)(packBase + setStride + (size_t)s*64*8);
      bias = decb;
    } else if (t == S_LEN + 1){             // dec-folded (y feedback in Whh)
      #pragma unroll
      for (int s = 0; s < 17; s++)
        Breg[s] = *(const half8*)(packBase + 2*setStride + (size_t)s*64*8);
      bias = decb + wihg*lbv;
    }

    // early x load (read-only, plain cached -> hides latency under poll)
    float xv = 0.f;
    if (t < S_LEN){
      if (tid < 128)
        xv = x_enc[(size_t)(r0 + (tid >> 3))*(S_LEN*8) + t*8 + (tid & 7)];
    } else if (t == S_LEN){
      if (tid < 16)
        xv = x_enc[(size_t)(r0 + tid)*(S_LEN*8) + 335*8 + 3];
    }

    // ---- wait for producers: wave0 lanes 0-15 poll ONE 64B line of flags
    if (t > 0 && w == 0){
      const unsigned tgt = (unsigned)t;
      for(;;){
        unsigned f = tgt;
        if (lane < 16)
          f = __hip_atomic_load(&blkflags[bg*16 + lane], __ATOMIC_RELAXED,
                                __HIP_MEMORY_SCOPE_AGENT);
        if (__all(f >= tgt)) break;
      }
    }
    __syncthreads();   // B1: h ready; prev step's MFMA reads of Abuf done

    // ---- stage h_{t-1} (coalesced 32B/thread -> swizzled LDS)
    if (t > 0){
      const ull* hs = h_buf + ((size_t)(((t-1)&1)*B_SZ + r0 + srow))*128 + sseg*4;
      ull d0 = __hip_atomic_load(hs+0, __ATOMIC_RELAXED, __HIP_MEMORY_SCOPE_AGENT);
      ull d1 = __hip_atomic_load(hs+1, __ATOMIC_RELAXED, __HIP_MEMORY_SCOPE_AGENT);
      ull d2 = __hip_atomic_load(hs+2, __ATOMIC_RELAXED, __HIP_MEMORY_SCOPE_AGENT);
      ull d3 = __hip_atomic_load(hs+3, __ATOMIC_RELAXED, __HIP_MEMORY_SCOPE_AGENT);
      uint4 A;  A.x = (unsigned)d0; A.y = (unsigned)(d0>>32);
                A.z = (unsigned)d1; A.w = (unsigned)(d1>>32);
      uint4 Bv; Bv.x = (unsigned)d2; Bv.y = (unsigned)(d2>>32);
                Bv.z = (unsigned)d3; Bv.w = (unsigned)(d3>>32);
      *(uint4*)&Abuf[srow*1152 + ((sseg*32     ) ^ ssw)] = A;
      *(uint4*)&Abuf[srow*1152 + ((sseg*32 + 16) ^ ssw)] = Bv;
    }
    // ---- stage x tail
    if (t < S_LEN){
      if (tid < 128){
        int r = tid >> 3, f = tid & 7;
        *(_Float16*)&Abuf[r*1152 + (1024 ^ ((r & 7) << 4)) + f*2] = (_Float16)xv;
      }
      if (t == 0 && tid >= 256 && tid < 304){
        int idx = tid - 256;                 // zero k=520..543 once (persists)
        int r = idx & 15, u = 1 + (idx >> 4);
        uint4 z = {0, 0, 0, 0};
        *(uint4*)&Abuf[r*1152 + ((1024 + u*16) ^ ((r & 7) << 4))] = z;
      }
    } else if (t == S_LEN){
      if (tid < 16){
        half8 va;
        #pragma unroll
        for (int q = 0; q < 8; q++) va[q] = (_Float16)0.f;
        va[0] = (_Float16)xv;
        *(half8*)&Abuf[tid*1152 + (1024 ^ ((tid & 7) << 4))] = va;
      }
    }
    __syncthreads();   // B2: A-tile complete

    // ---- gates = bias + [h | x] @ W^T
    f32x4 acc = {bias, bias, bias, bias};
    if (t == 0){       // h0 = 0: only the x K-tile contributes
      half8 a = *(const half8*)&Abuf[abase + ((1024 + hi*16) ^ asw)];
      acc = __builtin_amdgcn_mfma_f32_16x16x32_f16(a, Breg[16], acc, 0, 0, 0);
    } else {
      f32x4 acc1 = {0.f, 0.f, 0.f, 0.f};
      #pragma unroll
      for (int s = 0; s < 16; s += 2){
        half8 a0 = *(const half8*)&Abuf[abase + (((s  )*64 + hi*16) ^ asw)];
        half8 a1 = *(const half8*)&Abuf[abase + (((s+1)*64 + hi*16) ^ asw)];
        acc  = __builtin_amdgcn_mfma_f32_16x16x32_f16(a0, Breg[s],   acc,  0, 0, 0);
        acc1 = __builtin_amdgcn_mfma_f32_16x16x32_f16(a1, Breg[s+1], acc1, 0, 0, 0);
      }
      if (t <= S_LEN){   // x/x_dec0 tail frag; folded decoder steps skip it
        half8 a16 = *(const half8*)&Abuf[abase + ((16*64 + hi*16) ^ asw)];
        acc = __builtin_amdgcn_mfma_f32_16x16x32_f16(a16, Breg[16], acc, 0, 0, 0);
      }
      acc = acc + acc1;
    }

    // ---- LSTM pointwise: gather i,f,g,o across lanes c, c^4, c^8, c^12
    float hold[4];
    #pragma unroll
    for (int j = 0; j < 4; j++){
      float a   = acc[j];
      float x4  = __shfl_xor(a, 4);
      float x8  = __shfl_xor(a, 8);
      float x12 = __shfl_xor(x4, 8);
      float gi, gf, gg, go;
      if      (gatei == 0){ gi = a;   gf = x4;  gg = x8;  go = x12; }
      else if (gatei == 1){ gi = x4;  gf = a;   gg = x12; go = x8;  }
      else if (gatei == 2){ gi = x8;  gf = x12; gg = a;   go = x4;  }
      else                { gi = x12; gf = x8;  gg = x4;  go = a;   }
      float cn = sigf(gf)*c4[j] + sigf(gi)*tanh_fast(gg);
      c4[j] = cn;
      hold[j] = sigf(go)*tanh_fast(cn);
    }

    // ---- 4x4 lane transpose within each col16-quad -> one 8B store per lane
    unsigned short s16[4];
    #pragma unroll
    for (int j = 0; j < 4; j++)
      s16[j] = __builtin_bit_cast(unsigned short, (_Float16)hold[j]);
    unsigned lo01 = (unsigned)s16[0] | ((unsigned)s16[1] << 16);
    unsigned hi23 = (unsigned)s16[2] | ((unsigned)s16[3] << 16);
    const bool qlow = (q4 < 2), up = (q4 & 1);
    unsigned sendA = qlow ? hi23 : lo01;
    unsigned rA    = (unsigned)__shfl_xor((int)sendA, 2);
    unsigned keepA = qlow ? lo01 : hi23;
    unsigned vq_p  = up ? (keepA & 0xffffu) : (keepA >> 16);
    unsigned vqx_p = up ? (rA    & 0xffffu) : (rA    >> 16);
    unsigned sendB = qlow ? (vq_p | (vqx_p << 16)) : (vqx_p | (vq_p << 16));
    unsigned rB    = (unsigned)__shfl_xor((int)sendB, 1);
    unsigned vq_m  = up ? (keepA >> 16) : (keepA & 0xffffu);
    unsigned vqx_m = up ? (rA    >> 16) : (rA    & 0xffffu);
    unsigned ownB  = qlow ? (vq_m | (vqx_m << 16)) : (vqx_m | (vq_m << 16));
    unsigned w0 = up ? ((rB & 0xffffu) | (ownB << 16)) : ((ownB & 0xffffu) | (rB << 16));
    unsigned w1 = up ? ((rB >> 16) | (ownB & 0xffff0000u))
                     : ((ownB >> 16) | (rB & 0xffff0000u));
    if (gatei == 0){
      ull hv = (ull)w0 | ((ull)w1 << 32);
      int row = hi*4 + q4;
      __hip_atomic_store(h_buf + ((size_t)((t&1)*B_SZ + r0 + row))*128 + og*8 + w,
                         hv, __ATOMIC_RELAXED, __HIP_MEMORY_SCOPE_AGENT);
    }

    // ---- publish: own-wave drain -> LDS arrival bump -> LAST wave stores flag
    asm volatile("s_waitcnt vmcnt(0)" ::: "memory");
    if (lane == 0){
      unsigned old = atomicAdd(&lds_arrive, 1u);
      if (old == (unsigned)(t*8 + 7))       // all 8 waves drained their stores
        __hip_atomic_store(&blkflags[bg*16 + og], (unsigned)(t + 1),
                           __ATOMIC_RELAXED, __HIP_MEMORY_SCOPE_AGENT);
    }

    // ---- decoder outputs: conflict-free per-(og,wave) slot (off crit path)
    if (t >= S_LEN){
      #pragma unroll
      for (int j = 0; j < 4; j++){
        float pv = (gatei == 0) ? hold[j]*linw : 0.f;
        pv += __shfl_xor(pv, 1);
        pv += __shfl_xor(pv, 2);
        if (col16 == 0)
          __hip_atomic_store(
              &y_buf[((size_t)(t - S_LEN)*B_SZ + r0 + hi*4 + j)*128 + og*8 + w],
              pv, __ATOMIC_RELAXED, __HIP_MEMORY_SCOPE_AGENT);
      }
    }
  }
}

extern "C" void kernel_launch(void* const* d_in, const int* in_sizes, int n_in,
                              void* d_out, int out_size, void* d_ws, size_t ws_size,
                              hipStream_t stream) {
  const float* x_enc   = (const float*)d_in[0];
  const float* enc_Wih = (const float*)d_in[1];
  const float* enc_Whh = (const float*)d_in[2];
  const float* enc_b   = (const float*)d_in[3];
  const float* dec_Wih = (const float*)d_in[4];
  const float* dec_Whh = (const float*)d_in[5];
  const float* dec_b   = (const float*)d_in[6];
  const float* lin_W   = (const float*)d_in[7];
  const float* lin_b   = (const float*)d_in[8];

  char* ws = (char*)d_ws;
  _Float16* pack  = (_Float16*)(ws + OFF_PACK);
  ull*      h_buf = (ull*)(ws + OFF_HBUF);
  float*    y_buf = (float*)(ws + OFF_YBUF);
  unsigned int* blkflags = (unsigned int*)(ws + OFF_FLG);

  // zero flags (monotonic from 0 each launch; deterministic across replays)
  hipMemsetAsync(ws + OFF_FLG, 0, SZ_FLG, stream);

  pack_weights<<<dim3(17, 8, 16), 64, 0, stream>>>(enc_Whh, enc_Wih, lin_W,
                                                   pack, 0);
  pack_weights<<<dim3(17, 8, 16), 64, 0, stream>>>(dec_Whh, dec_Wih, lin_W,
                                                   pack + SZ_PACK/2, 1);
  pack_weights<<<dim3(17, 8, 16), 64, 0, stream>>>(dec_Whh, dec_Wih, lin_W,
                                                   pack + SZ_PACK, 2);

  void* args[] = { (void*)&x_enc, (void*)&enc_b, (void*)&dec_b, (void*)&dec_Wih,
                   (void*)&lin_W, (void*)&lin_b, (void*)&pack,
                   (void*)&h_buf, (void*)&y_buf, (void*)&blkflags };
  hipLaunchCooperativeKernel((void*)lstm_main, dim3(256), dim3(512),
                             args, 0, stream);

  finalize_out<<<dim3((B_SZ*P_LEN)/256), 256, 0, stream>>>(y_buf, lin_b, (float*)d_out);
}